// Round 8
// baseline (251.401 us; speedup 1.0000x reference)
//
#include <hip/hip_runtime.h>
#include <stdint.h>

#define NN 65536
#define BB 64
#define TPB 256

// FPS/convert geometry: 32 blocks/batch, 2048 pts/block, 8 pts/thread
#define BPB 32
#define FGRID (BB * BPB)       // 2048 blocks
#define PPB 2048
#define LPT 8

// Gather geometry (proven baseline): 16 blocks/batch, 4096 rows/block
#define GBPB 16
#define GGRID (BB * GBPB)      // 1024
#define GLPT 16

// Exact-fp32 squared distance, matching numpy's ((dx*dx + dy*dy) + dz*dz)
// with no FMA contraction (rn intrinsics are never fused).
__device__ __forceinline__ float sqdist(float x, float y, float z,
                                        float cx, float cy, float cz) {
    float dx = __fsub_rn(x, cx);
    float dy = __fsub_rn(y, cy);
    float dz = __fsub_rn(z, cz);
    return __fadd_rn(__fadd_rn(__fmul_rn(dx, dx), __fmul_rn(dy, dy)),
                     __fmul_rn(dz, dz));
}

// Packed argmax key: (fp32 bits << 32) | (0xFFFFFFFF - index).
// Distances >= 0 so fp32 bit order == value order; ~index makes u64-max
// prefer the SMALLEST index on value ties (np.argmax semantics).
__device__ __forceinline__ unsigned long long pack_key(float v, int i) {
    return ((unsigned long long)__float_as_uint(v) << 32) |
           (unsigned long long)(0xFFFFFFFFu - (unsigned)i);
}
__device__ __forceinline__ int key_idx(unsigned long long key) {
    return (int)(0xFFFFFFFFu - (unsigned)(key & 0xFFFFFFFFu));
}

// select r-th (0-based, from LSB) set bit of m
__device__ __forceinline__ int sel_bit(uint64_t m, int r) {
    int bit = 0;
    int c = __popcll(m & 0xFFFFFFFFull);
    if (r >= c) { r -= c; m >>= 32; bit += 32; }
    c = __popcll(m & 0xFFFFull);
    if (r >= c) { r -= c; m >>= 16; bit += 16; }
    c = __popcll(m & 0xFFull);
    if (r >= c) { r -= c; m >>= 8; bit += 8; }
    c = __popcll(m & 0xFull);
    if (r >= c) { r -= c; m >>= 4; bit += 4; }
    c = __popcll(m & 0x3ull);
    if (r >= c) { r -= c; m >>= 2; bit += 2; }
    if (r >= (int)(m & 1ull)) { bit += 1; }
    return bit;
}

// Reduce the 32 partial keys of batch b from pass slot a (redundant per
// thread — broadcast loads, cheap) -> winning point index.
__device__ __forceinline__ int reduce_part(const unsigned long long* partKey,
                                           int a, int b) {
    const unsigned long long* s = partKey + a * FGRID + b * BPB;
    unsigned long long bk = s[0];
    #pragma unroll
    for (int w = 1; w < BPB; ++w) bk = (s[w] > bk) ? s[w] : bk;
    return key_idx(bk);
}

// Block argmax reduce + store of this block's partial key.
__device__ __forceinline__ void store_partial(float bestv, int besti,
                                              unsigned long long* slot,
                                              int tid, int lane, int wid) {
    unsigned long long key = pack_key(bestv, besti);
    #pragma unroll
    for (int off = 32; off > 0; off >>= 1) {
        unsigned long long ok = __shfl_down(key, off, 64);
        if (ok > key) key = ok;
    }
    __shared__ unsigned long long s_k[4];
    if (lane == 0) s_k[wid] = key;
    __syncthreads();
    if (tid == 0) {
        unsigned long long bk = s_k[0];
        #pragma unroll
        for (int w = 1; w < 4; ++w) bk = (s_k[w] > bk) ? s_k[w] : bk;
        *slot = bk;
    }
}

// =====================================================================
// K0: one pass over the AoS input. Emits compact SoA planes X/Y/Z
// (12 B/pt instead of re-streaming 24 B records every pass), initial
// min-distance MD (vs center 0 = point 0), and pass-0 argmax partials.
// =====================================================================
__global__ __launch_bounds__(TPB) void convert_init(
        const float* __restrict__ pts,
        float* __restrict__ X, float* __restrict__ Y,
        float* __restrict__ Z, float* __restrict__ MD,
        unsigned long long* __restrict__ partKey) {
    const int gb = blockIdx.x;
    const int b = gb >> 5, blk = gb & 31;
    const int tid = threadIdx.x;
    const int lane = tid & 63, wid = tid >> 6;
    const float* base = pts + (size_t)b * NN * 6;
    float* Xb = X + (size_t)b * NN;
    float* Yb = Y + (size_t)b * NN;
    float* Zb = Z + (size_t)b * NN;
    float* Mb = MD + (size_t)b * NN;

    const float cx = base[0], cy = base[1], cz = base[2];

    float bestv = -1.0f; int besti = 0x7fffffff;
    #pragma unroll
    for (int l = 0; l < LPT; ++l) {
        const int p = blk * PPB + l * TPB + tid;    // coalesced across lanes
        const float* q = base + (size_t)p * 6;
        float2 xy = *(const float2*)q;              // p*24 is 8B-aligned
        float  zz = q[2];
        float d = sqdist(xy.x, xy.y, zz, cx, cy, cz);
        Xb[p] = xy.x; Yb[p] = xy.y; Zb[p] = zz; Mb[p] = d;
        if (d > bestv) { bestv = d; besti = p; }    // ascending p: earliest tie
    }
    store_partial(bestv, besti, &partKey[0 * FGRID + gb], tid, lane, wid);
}

// =====================================================================
// K1/K2: FPS middle pass K (selects center K, prepares argmax for K+1).
// Reads planes + MD (84 MB, L3-resident), float4-vectorized: each thread
// owns 8 CONSECUTIVE points (2x float4 per plane). min-update is the
// same left-fold fminf chain as the reference -> bitwise identical.
// =====================================================================
template<int K>
__global__ __launch_bounds__(TPB) void fps_mid(
        const float* __restrict__ X, const float* __restrict__ Y,
        const float* __restrict__ Z, float* __restrict__ MD,
        unsigned long long* __restrict__ partKey) {
    const int gb = blockIdx.x;
    const int b = gb >> 5, blk = gb & 31;
    const int tid = threadIdx.x;
    const int lane = tid & 63, wid = tid >> 6;
    const float* Xb = X + (size_t)b * NN;
    const float* Yb = Y + (size_t)b * NN;
    const float* Zb = Z + (size_t)b * NN;
    float* Mb = MD + (size_t)b * NN;

    const int idx = reduce_part(partKey, K - 1, b);
    const float cx = Xb[idx], cy = Yb[idx], cz = Zb[idx];   // broadcast loads

    const int p0 = blk * PPB + tid * 8;             // 8 consecutive pts/thread
    float4 x0 = *(const float4*)(Xb + p0), x1 = *(const float4*)(Xb + p0 + 4);
    float4 y0 = *(const float4*)(Yb + p0), y1 = *(const float4*)(Yb + p0 + 4);
    float4 z0 = *(const float4*)(Zb + p0), z1 = *(const float4*)(Zb + p0 + 4);
    float4 m0 = *(const float4*)(Mb + p0), m1 = *(const float4*)(Mb + p0 + 4);

    float xs[8] = {x0.x,x0.y,x0.z,x0.w,x1.x,x1.y,x1.z,x1.w};
    float ys[8] = {y0.x,y0.y,y0.z,y0.w,y1.x,y1.y,y1.z,y1.w};
    float zs[8] = {z0.x,z0.y,z0.z,z0.w,z1.x,z1.y,z1.z,z1.w};
    float ms[8] = {m0.x,m0.y,m0.z,m0.w,m1.x,m1.y,m1.z,m1.w};

    float bestv = -1.0f; int besti = 0x7fffffff;
    #pragma unroll
    for (int i = 0; i < 8; ++i) {
        float d = fminf(ms[i], sqdist(xs[i], ys[i], zs[i], cx, cy, cz));
        ms[i] = d;
        if (d > bestv) { bestv = d; besti = p0 + i; }   // ascending index
    }
    *(float4*)(Mb + p0)     = make_float4(ms[0], ms[1], ms[2], ms[3]);
    *(float4*)(Mb + p0 + 4) = make_float4(ms[4], ms[5], ms[6], ms[7]);

    store_partial(bestv, besti, &partKey[K * FGRID + gb], tid, lane, wid);
}

// =====================================================================
// K3: final FPS pass (center 3) fused with the keep-mask ballot.
// Needs the strided lane->point mapping so ballot bit L == point p0+L.
// =====================================================================
__global__ __launch_bounds__(TPB) void fps_mask(
        const float* __restrict__ X, const float* __restrict__ Y,
        const float* __restrict__ Z, const float* __restrict__ MD,
        const unsigned long long* __restrict__ partKey,
        uint64_t* __restrict__ masks) {
    const int gb = blockIdx.x;
    const int b = gb >> 5, blk = gb & 31;
    const int tid = threadIdx.x;
    const int lane = tid & 63, wid = tid >> 6;
    const float* Xb = X + (size_t)b * NN;
    const float* Yb = Y + (size_t)b * NN;
    const float* Zb = Z + (size_t)b * NN;
    const float* Mb = MD + (size_t)b * NN;

    const int idx = reduce_part(partKey, 2, b);
    const float cx = Xb[idx], cy = Yb[idx], cz = Zb[idx];
    uint64_t* mb = masks + (size_t)b * 1024;

    #pragma unroll
    for (int l = 0; l < LPT; ++l) {
        const int p = blk * PPB + l * TPB + tid;
        float d = fminf(Mb[p], sqdist(Xb[p], Yb[p], Zb[p], cx, cy, cz));
        // sqrt_rn is monotone & correctly rounded: sqrt(min d^2)==min(norm)
        int keep = (__fsqrt_rn(d) >= 0.2f) ? 1 : 0;
        uint64_t m = __ballot(keep);                // bit L == point p0 + L
        if (lane == 0) mb[blk * 32 + l * 4 + wid] = m;
    }
}

// =====================================================================
// K4: fused compaction + cyclic gather (proven baseline kernel verbatim).
// =====================================================================
__global__ __launch_bounds__(TPB) void gather_kernel(
        const float* __restrict__ pts, const uint64_t* __restrict__ masks,
        float* __restrict__ out) {
    const int gb = blockIdx.x;
    const int b = gb >> 4, blk = gb & 15;
    const int tid = threadIdx.x;
    const int lane = tid & 63, wid = tid >> 6;
    __shared__ uint64_t s_m[1024];
    __shared__ int s_pre[1024];
    __shared__ int s_ws[4], s_wo[4];
    __shared__ int s_nv;

    const uint64_t* mb = masks + (size_t)b * 1024;
    uint64_t w[4];
    int cnt = 0;
    #pragma unroll
    for (int k = 0; k < 4; ++k) {
        w[k] = mb[tid * 4 + k];
        s_m[tid * 4 + k] = w[k];
        cnt += __popcll(w[k]);
    }
    int incl = cnt;
    #pragma unroll
    for (int off = 1; off < 64; off <<= 1) {
        int v = __shfl_up(incl, off, 64);
        if (lane >= off) incl += v;
    }
    if (lane == 63) s_ws[wid] = incl;
    __syncthreads();
    if (tid == 0) {
        int run = 0;
        #pragma unroll
        for (int q = 0; q < 4; ++q) { s_wo[q] = run; run += s_ws[q]; }
        s_nv = run;
    }
    __syncthreads();
    int run = s_wo[wid] + incl - cnt;
    #pragma unroll
    for (int k = 0; k < 4; ++k) {
        s_pre[tid * 4 + k] = run;
        run += __popcll(w[k]);
    }
    __syncthreads();

    const int nv = s_nv;
    const float* baseP = pts + (size_t)b * NN * 6;
    float* ob = out + (size_t)b * NN * 6;

    if (nv <= 0) {
        float2 zz = make_float2(0.f, 0.f);
        #pragma unroll
        for (int l = 0; l < GLPT; ++l) {
            int j = blk * 4096 + l * TPB + tid;
            float2* o = (float2*)(ob + (size_t)j * 6);
            o[0] = zz; o[1] = zz; o[2] = zz;
        }
        return;
    }

    #pragma unroll
    for (int l = 0; l < GLPT; ++l) {
        int j = blk * 4096 + l * TPB + tid;
        int jj = (int)((unsigned)j % (unsigned)nv);
        int wd = 0;
        #pragma unroll
        for (int s = 512; s > 0; s >>= 1) {
            int cand = wd + s;
            if (cand < 1024 && s_pre[cand] <= jj) wd = cand;
        }
        int src = wd * 64 + sel_bit(s_m[wd], jj - s_pre[wd]);
        const float2* p = (const float2*)(baseP + (size_t)src * 6);
        float2* o = (float2*)(ob + (size_t)j * 6);
        float2 r0 = p[0], r1 = p[1], r2 = p[2];
        o[0] = r0; o[1] = r1; o[2] = r2;
    }
}

extern "C" void kernel_launch(void* const* d_in, const int* in_sizes, int n_in,
                              void* d_out, int out_size, void* d_ws, size_t ws_size,
                              hipStream_t stream) {
    const float* pts = (const float*)d_in[0];
    float* out = (float*)d_out;

    // workspace layout (every word written before read each call; no memset):
    //   partKey @ 0        : 3*2048*8 = 48 KB
    //   masks   @ 64 KB    : 512 KB
    //   planes  @ 1 MB     : X, Y, Z, MD — 4 x 16 MB = 64 MB
    const size_t S = (size_t)BB * NN * sizeof(float);   // 16 MB per plane
    unsigned long long* partKey = (unsigned long long*)d_ws;
    uint64_t* masks = (uint64_t*)((char*)d_ws + (64 << 10));
    char* pb = (char*)d_ws + (1 << 20);
    float* X  = (float*)(pb);
    float* Y  = (float*)(pb + S);
    float* Z  = (float*)(pb + 2 * S);
    float* MD = (float*)(pb + 3 * S);

    convert_init<<<FGRID, TPB, 0, stream>>>(pts, X, Y, Z, MD, partKey);
    fps_mid<1><<<FGRID, TPB, 0, stream>>>(X, Y, Z, MD, partKey);
    fps_mid<2><<<FGRID, TPB, 0, stream>>>(X, Y, Z, MD, partKey);
    fps_mask<<<FGRID, TPB, 0, stream>>>(X, Y, Z, MD, partKey, masks);
    gather_kernel<<<GGRID, TPB, 0, stream>>>(pts, masks, out);
}

// Round 9
// 245.710 us; speedup vs baseline: 1.0232x; 1.0232x over previous
//
#include <hip/hip_runtime.h>
#include <stdint.h>

#define NN 65536
#define BB 64
#define TPB 256

// ---------------- fused geometry: 16 blocks/batch, 4096 pts/block, 16/thread
#define BPB 16
#define GRID_BLKS (BB * BPB)   // 1024 = 4 blocks/CU * 256 CU
#define PPB 4096
#define LPT 16
#define WPB (PPB / 64)         // 64 mask words per block

// ---------------- fallback (proven baseline) geometry
#define FBPB 32
#define FGRID (BB * FBPB)      // 2048
#define FPPB 2048
#define FLPT 8
#define GBPB 16
#define GGRID (BB * GBPB)      // 1024
#define GLPT 16

// Exact-fp32 squared distance, matching numpy's ((dx*dx + dy*dy) + dz*dz)
// with no FMA contraction (rn intrinsics are never fused).
__device__ __forceinline__ float sqdist(float x, float y, float z,
                                        float cx, float cy, float cz) {
    float dx = __fsub_rn(x, cx);
    float dy = __fsub_rn(y, cy);
    float dz = __fsub_rn(z, cz);
    return __fadd_rn(__fadd_rn(__fmul_rn(dx, dx), __fmul_rn(dy, dy)),
                     __fmul_rn(dz, dz));
}

// Packed argmax key: (fp32 bits << 32) | (0xFFFFFFFF - index).
__device__ __forceinline__ unsigned long long pack_key(float v, int i) {
    return ((unsigned long long)__float_as_uint(v) << 32) |
           (unsigned long long)(0xFFFFFFFFu - (unsigned)i);
}
__device__ __forceinline__ int key_idx(unsigned long long key) {
    return (int)(0xFFFFFFFFu - (unsigned)(key & 0xFFFFFFFFu));
}

// select r-th (0-based, from LSB) set bit of m
__device__ __forceinline__ int sel_bit(uint64_t m, int r) {
    int bit = 0;
    int c = __popcll(m & 0xFFFFFFFFull);
    if (r >= c) { r -= c; m >>= 32; bit += 32; }
    c = __popcll(m & 0xFFFFull);
    if (r >= c) { r -= c; m >>= 16; bit += 16; }
    c = __popcll(m & 0xFFull);
    if (r >= c) { r -= c; m >>= 8; bit += 8; }
    c = __popcll(m & 0xFull);
    if (r >= c) { r -= c; m >>= 4; bit += 4; }
    c = __popcll(m & 0x3ull);
    if (r >= c) { r -= c; m >>= 2; bit += 2; }
    if (r >= (int)(m & 1ull)) { bit += 1; }
    return bit;
}

// ---- per-batch sense-reversing barrier (r4/r5/r7 protocol, verified 3x):
// plain data stores/loads; tid0 ACQ_REL fetch_add arrival; RELAXED spin with
// s_sleep; one agent ACQUIRE fence on wake.
template<int NB>
__device__ __forceinline__ void batch_barrier(unsigned* cnt, unsigned* gen) {
    __syncthreads();
    if (threadIdx.x == 0) {
        unsigned g = __hip_atomic_load(gen, __ATOMIC_RELAXED,
                                       __HIP_MEMORY_SCOPE_AGENT);
        unsigned a = __hip_atomic_fetch_add(cnt, 1u, __ATOMIC_ACQ_REL,
                                            __HIP_MEMORY_SCOPE_AGENT) + 1u;
        if (a == (unsigned)NB) {
            __hip_atomic_store(cnt, 0u, __ATOMIC_RELAXED,
                               __HIP_MEMORY_SCOPE_AGENT);
            __hip_atomic_store(gen, g + 1u, __ATOMIC_RELEASE,
                               __HIP_MEMORY_SCOPE_AGENT);
        } else {
            while (__hip_atomic_load(gen, __ATOMIC_RELAXED,
                                     __HIP_MEMORY_SCOPE_AGENT) == g)
                __builtin_amdgcn_s_sleep(4);
            __builtin_amdgcn_fence(__ATOMIC_ACQUIRE, "agent");
        }
    }
    __syncthreads();
}

__global__ void init_barrier(unsigned* bar) {
    const int t = threadIdx.x;   // 64 threads, one 128B line each
    bar[t * 32 + 0] = 0u;
    bar[t * 32 + 1] = 0u;
}

// =====================================================================
// Fused kernel, r9. Unified model from r3-r8: post-fence streaming reads
// run at ~2.2 TB/s (L2 invalidated by every acquire), so FPS re-scans
// MUST come from on-chip state. Register attempts failed twice (r4
// remat at cap-128-unused; r5/r7 spill at cap-64 -> VGPR=32). This
// config: xy in a 32 KB LDS plane (thread reads ONLY ITS OWN slots —
// LDS as compiler-proof private storage), z[16]+md[16] in regs, cap 128
// via launch_bounds(256,4) -> 4 blocks/CU -> 1024 blocks co-resident.
// Epilogue = rank scatter (verified r5/r7), union-overlaid on dead xy.
// =====================================================================
union Shm {
    float2 xy[PPB];                                  // 32 KB (load + FPS)
    struct { uint64_t m[1024]; int pre[1024]; } e;   // 12 KB (epilogue)
};

__global__ __launch_bounds__(TPB, 4) void fused_kernel(
        const float* __restrict__ pts,
        unsigned long long* __restrict__ partKey,
        uint64_t* __restrict__ masks,
        float* __restrict__ out,
        unsigned* __restrict__ bar) {
    const int gb = blockIdx.x;
    const int b = gb >> 4, blk = gb & 15;
    const int tid = threadIdx.x;
    const int lane = tid & 63, wid = tid >> 6;
    const float* base = pts + (size_t)b * NN * 6;
    unsigned* bcnt = bar + b * 32;
    unsigned* bgen = bar + b * 32 + 1;

    __shared__ Shm shm;
    __shared__ unsigned long long s_k[4];
    __shared__ int s_ws[4], s_wo[4];
    __shared__ int s_nv;

    // ---- load once: xy -> own LDS slots, z -> regs, md -> regs ----
    const float c0x = base[0], c0y = base[1], c0z = base[2];
    float z[LPT], md[LPT];
    #pragma unroll
    for (int l = 0; l < LPT; ++l) {
        const int q = l * TPB + tid;                // block-local point idx
        const int p = blk * PPB + q;                // batch point idx
        const float* src = base + (size_t)p * 6;
        float2 xy = *(const float2*)src;            // p*24 is 8B-aligned
        shm.xy[q] = xy;
        z[l] = src[2];
        md[l] = sqdist(xy.x, xy.y, z[l], c0x, c0y, c0z);   // center 0 = pt 0
    }
    // pin z against rematerialization (r4 failure mode); 16 regs.
    #pragma unroll
    for (int l = 0; l < LPT; ++l) asm volatile("" : "+v"(z[l]));

    // ---- FPS: centers 1..3 via per-batch argmax of md ----
    // Incremental fminf chain == sequential jnp.minimum chain bitwise.
    for (int k = 0; k < 3; ++k) {
        float bestv = -1.0f; int besti = 0x7fffffff;
        #pragma unroll
        for (int l = 0; l < LPT; ++l) {
            if (md[l] > bestv) { bestv = md[l]; besti = blk * PPB + l * TPB + tid; }
        }   // ascending index order -> strict '>' keeps earliest on ties
        unsigned long long key = pack_key(bestv, besti);
        #pragma unroll
        for (int off = 32; off > 0; off >>= 1) {
            unsigned long long ok = __shfl_down(key, off, 64);
            if (ok > key) key = ok;
        }
        if (lane == 0) s_k[wid] = key;
        __syncthreads();
        if (tid == 0) {
            unsigned long long bk = s_k[0];
            #pragma unroll
            for (int w = 1; w < 4; ++w) bk = (s_k[w] > bk) ? s_k[w] : bk;
            partKey[k * GRID_BLKS + gb] = bk;       // plain store; barrier orders
        }
        batch_barrier<BPB>(bcnt, bgen);

        // parallel reduce of the batch's 16 partials via xor-shuffle max
        const unsigned long long* s = partKey + k * GRID_BLKS + b * BPB;
        unsigned long long bk = s[lane & (BPB - 1)];
        #pragma unroll
        for (int off = 32; off > 0; off >>= 1) {
            unsigned long long ok = __shfl_xor(bk, off, 64);
            if (ok > bk) bk = ok;
        }
        const float* cp = base + (size_t)key_idx(bk) * 6;  // broadcast load
        const float cx = cp[0], cy = cp[1], cz = cp[2];
        // md update: pure LDS (own slots) + VALU — no global traffic.
        #pragma unroll
        for (int l = 0; l < LPT; ++l) {
            float2 xy = shm.xy[l * TPB + tid];
            md[l] = fminf(md[l], sqdist(xy.x, xy.y, z[l], cx, cy, cz));
        }
    }

    // ---- keep bits -> ballot -> mask words (only md used; xy dead) ----
    uint64_t* mb = masks + (size_t)b * 1024;
    #pragma unroll
    for (int l = 0; l < LPT; ++l) {
        // sqrt_rn is monotone & correctly rounded: sqrt(min d^2)==min(norm)
        int keep = (__fsqrt_rn(md[l]) >= 0.2f) ? 1 : 0;
        uint64_t m = __ballot(keep);                // bit L == point p0 + L
        if (lane == 0) mb[blk * WPB + l * 4 + wid] = m;   // plain store
    }
    batch_barrier<BPB>(bcnt, bgen);   // entry __syncthreads retires xy reads
                                      // before shm.e overlays the union

    // ---- batch-wide prefix over the 1024 mask words (every block) ----
    uint64_t w[4];
    int cnt = 0;
    #pragma unroll
    for (int kk = 0; kk < 4; ++kk) {
        w[kk] = mb[tid * 4 + kk];                   // plain coalesced loads
        shm.e.m[tid * 4 + kk] = w[kk];
        cnt += __popcll(w[kk]);
    }
    int incl = cnt;
    #pragma unroll
    for (int off = 1; off < 64; off <<= 1) {
        int v = __shfl_up(incl, off, 64);
        if (lane >= off) incl += v;
    }
    if (lane == 63) s_ws[wid] = incl;
    __syncthreads();
    if (tid == 0) {
        int run = 0;
        #pragma unroll
        for (int q = 0; q < 4; ++q) { s_wo[q] = run; run += s_ws[q]; }
        s_nv = run;
    }
    __syncthreads();
    int run = s_wo[wid] + incl - cnt;               // exclusive offset, word 4t
    #pragma unroll
    for (int kk = 0; kk < 4; ++kk) {
        shm.e.pre[tid * 4 + kk] = run;
        run += __popcll(w[kk]);
    }
    __syncthreads();

    const int nv = s_nv;
    float* ob = out + (size_t)b * NN * 6;

    if (nv <= 0) {                                  // all dropped -> zeros
        float2 zz = make_float2(0.f, 0.f);
        #pragma unroll
        for (int l = 0; l < LPT; ++l) {
            int j = blk * PPB + l * TPB + tid;
            float2* o = (float2*)(ob + (size_t)j * 6);
            o[0] = zz; o[1] = zz; o[2] = zz;
        }
        return;
    }

    // ---- primary outputs: rank SCATTER (stable compaction order) ----
    // rank(p) = pre[word(p)] + popcount(mask below lane); kept lanes write
    // contiguous ranks -> dense coalesced 24B stores.
    #pragma unroll
    for (int l = 0; l < LPT; ++l) {
        const int p = blk * PPB + l * TPB + tid;
        const int w_idx = blk * WPB + l * 4 + wid;  // wave-uniform
        uint64_t m = shm.e.m[w_idx];
        int rank = shm.e.pre[w_idx] + __popcll(m & ((1ull << lane) - 1ull));
        if ((m >> lane) & 1ull) {
            const float2* q = (const float2*)(base + (size_t)p * 6);
            float2* o = (float2*)(ob + (size_t)rank * 6);
            float2 r0 = q[0], r1 = q[1], r2 = q[2];
            o[0] = r0; o[1] = r1; o[2] = r2;
        }
    }

    // ---- cyclic tail [nv, NN): small on this data; binary-search select ----
    const int T = NN - nv;
    if (T > 0) {
        const int chunk = (T + BPB - 1) / BPB;
        const int j0 = nv + blk * chunk;
        const int j1 = (j0 + chunk < NN) ? (j0 + chunk) : NN;
        for (int j = j0 + tid; j < j1; j += TPB) {
            unsigned jj = (unsigned)j % (unsigned)nv;
            int wd = 0;
            #pragma unroll
            for (int s2 = 512; s2 > 0; s2 >>= 1) {
                int cand = wd + s2;
                if (cand < 1024 && shm.e.pre[cand] <= (int)jj) wd = cand;
            }
            int src = wd * 64 + sel_bit(shm.e.m[wd], (int)jj - shm.e.pre[wd]);
            const float2* q = (const float2*)(base + (size_t)src * 6);
            float2* o = (float2*)(ob + (size_t)j * 6);
            float2 r0 = q[0], r1 = q[1], r2 = q[2];
            o[0] = r0; o[1] = r1; o[2] = r2;
        }
    }
}

// =====================================================================
// Fallback: the proven 5-kernel pipeline (baseline, 247 us), verbatim.
// =====================================================================
__device__ __forceinline__ int reduce_part(const unsigned long long* partKey,
                                           int a, int b) {
    const unsigned long long* s = partKey + a * FGRID + b * FBPB;
    unsigned long long bk = s[0];
    #pragma unroll
    for (int w = 1; w < FBPB; ++w) bk = (s[w] > bk) ? s[w] : bk;
    return key_idx(bk);
}

template<int NC>
__global__ __launch_bounds__(TPB) void fps_pass(
        const float* __restrict__ pts, unsigned long long* partKey) {
    const int gb = blockIdx.x;
    const int b = gb >> 5, blk = gb & 31;
    const int tid = threadIdx.x;
    const int lane = tid & 63, wid = tid >> 6;
    const float* base = pts + (size_t)b * NN * 6;

    float cx[NC], cy[NC], cz[NC];
    cx[0] = base[0]; cy[0] = base[1]; cz[0] = base[2];
    #pragma unroll
    for (int k = 1; k < NC; ++k) {
        int idx = reduce_part(partKey, k - 1, b);
        const float* p = base + (size_t)idx * 6;
        cx[k] = p[0]; cy[k] = p[1]; cz[k] = p[2];
    }

    float bestv = -1.0f; int besti = 0x7fffffff;
    #pragma unroll
    for (int l = 0; l < FLPT; ++l) {
        const int p = blk * FPPB + l * TPB + tid;
        const float* q = base + (size_t)p * 6;
        float2 xy = *(const float2*)q;
        float  zz = q[2];
        float d = sqdist(xy.x, xy.y, zz, cx[0], cy[0], cz[0]);
        #pragma unroll
        for (int k = 1; k < NC; ++k)
            d = fminf(d, sqdist(xy.x, xy.y, zz, cx[k], cy[k], cz[k]));
        if (d > bestv) { bestv = d; besti = p; }
    }
    unsigned long long key = pack_key(bestv, besti);
    #pragma unroll
    for (int off = 32; off > 0; off >>= 1) {
        unsigned long long ok = __shfl_down(key, off, 64);
        if (ok > key) key = ok;
    }
    __shared__ unsigned long long s_k[4];
    if (lane == 0) s_k[wid] = key;
    __syncthreads();
    if (tid == 0) {
        unsigned long long bk = s_k[0];
        #pragma unroll
        for (int w = 1; w < 4; ++w) bk = (s_k[w] > bk) ? s_k[w] : bk;
        partKey[(NC - 1) * FGRID + gb] = bk;
    }
}

__global__ __launch_bounds__(TPB) void fps_final(
        const float* __restrict__ pts,
        const unsigned long long* __restrict__ partKey,
        uint64_t* __restrict__ masks) {
    const int gb = blockIdx.x;
    const int b = gb >> 5, blk = gb & 31;
    const int tid = threadIdx.x;
    const int lane = tid & 63, wid = tid >> 6;
    const float* base = pts + (size_t)b * NN * 6;

    float cx[4], cy[4], cz[4];
    cx[0] = base[0]; cy[0] = base[1]; cz[0] = base[2];
    #pragma unroll
    for (int k = 1; k < 4; ++k) {
        int idx = reduce_part(partKey, k - 1, b);
        const float* p = base + (size_t)idx * 6;
        cx[k] = p[0]; cy[k] = p[1]; cz[k] = p[2];
    }
    uint64_t* mb = masks + (size_t)b * 1024;

    #pragma unroll
    for (int l = 0; l < FLPT; ++l) {
        const int p = blk * FPPB + l * TPB + tid;
        const float* q = base + (size_t)p * 6;
        float2 xy = *(const float2*)q;
        float  zz = q[2];
        float d = sqdist(xy.x, xy.y, zz, cx[0], cy[0], cz[0]);
        #pragma unroll
        for (int k = 1; k < 4; ++k)
            d = fminf(d, sqdist(xy.x, xy.y, zz, cx[k], cy[k], cz[k]));
        int keep = (__fsqrt_rn(d) >= 0.2f) ? 1 : 0;
        uint64_t m = __ballot(keep);
        if (lane == 0) mb[blk * 32 + l * 4 + wid] = m;
    }
}

__global__ __launch_bounds__(TPB) void gather_kernel(
        const float* __restrict__ pts, const uint64_t* __restrict__ masks,
        float* __restrict__ out) {
    const int gb = blockIdx.x;
    const int b = gb >> 4, blk = gb & 15;
    const int tid = threadIdx.x;
    const int lane = tid & 63, wid = tid >> 6;
    __shared__ uint64_t s_m[1024];
    __shared__ int s_pre[1024];
    __shared__ int s_ws[4], s_wo[4];
    __shared__ int s_nv;

    const uint64_t* mb = masks + (size_t)b * 1024;
    uint64_t w[4];
    int cnt = 0;
    #pragma unroll
    for (int k = 0; k < 4; ++k) {
        w[k] = mb[tid * 4 + k];
        s_m[tid * 4 + k] = w[k];
        cnt += __popcll(w[k]);
    }
    int incl = cnt;
    #pragma unroll
    for (int off = 1; off < 64; off <<= 1) {
        int v = __shfl_up(incl, off, 64);
        if (lane >= off) incl += v;
    }
    if (lane == 63) s_ws[wid] = incl;
    __syncthreads();
    if (tid == 0) {
        int run = 0;
        #pragma unroll
        for (int q = 0; q < 4; ++q) { s_wo[q] = run; run += s_ws[q]; }
        s_nv = run;
    }
    __syncthreads();
    int run = s_wo[wid] + incl - cnt;
    #pragma unroll
    for (int k = 0; k < 4; ++k) {
        s_pre[tid * 4 + k] = run;
        run += __popcll(w[k]);
    }
    __syncthreads();

    const int nv = s_nv;
    const float* baseP = pts + (size_t)b * NN * 6;
    float* ob = out + (size_t)b * NN * 6;

    if (nv <= 0) {
        float2 zz = make_float2(0.f, 0.f);
        #pragma unroll
        for (int l = 0; l < GLPT; ++l) {
            int j = blk * 4096 + l * TPB + tid;
            float2* o = (float2*)(ob + (size_t)j * 6);
            o[0] = zz; o[1] = zz; o[2] = zz;
        }
        return;
    }

    #pragma unroll
    for (int l = 0; l < GLPT; ++l) {
        int j = blk * 4096 + l * TPB + tid;
        int jj = (int)((unsigned)j % (unsigned)nv);
        int wd = 0;
        #pragma unroll
        for (int s = 512; s > 0; s >>= 1) {
            int cand = wd + s;
            if (cand < 1024 && s_pre[cand] <= jj) wd = cand;
        }
        int src = wd * 64 + sel_bit(s_m[wd], jj - s_pre[wd]);
        const float2* p = (const float2*)(baseP + (size_t)src * 6);
        float2* o = (float2*)(ob + (size_t)j * 6);
        float2 r0 = p[0], r1 = p[1], r2 = p[2];
        o[0] = r0; o[1] = r1; o[2] = r2;
    }
}

extern "C" void kernel_launch(void* const* d_in, const int* in_sizes, int n_in,
                              void* d_out, int out_size, void* d_ws, size_t ws_size,
                              hipStream_t stream) {
    const float* pts = (const float*)d_in[0];
    float* out = (float*)d_out;

    // workspace layout (no memset needed; barrier zeroed by init kernel)
    unsigned long long* partKey = (unsigned long long*)d_ws;        // up to 48KB
    unsigned* bar = (unsigned*)((char*)d_ws + (48 << 10));          // 8KB: 64 x 128B
    uint64_t* masks = (uint64_t*)((char*)d_ws + (64 << 10));        // 512KB

    // One-time residency gate (pure host queries; capture-safe).
    static int mode = -1;
    if (mode < 0) {
        int dev = 0;
        (void)hipGetDevice(&dev);
        int ncu = 0, nb = 0;
        hipError_t e1 = hipDeviceGetAttribute(&ncu, hipDeviceAttributeMultiprocessorCount, dev);
        hipError_t e2 = hipOccupancyMaxActiveBlocksPerMultiprocessor(
            &nb, (const void*)fused_kernel, TPB, 0);
        mode = (e1 == hipSuccess && e2 == hipSuccess &&
                (long)nb * (long)ncu >= (long)GRID_BLKS) ? 1 : 0;
    }

    if (mode == 1) {
        init_barrier<<<1, 64, 0, stream>>>(bar);
        fused_kernel<<<GRID_BLKS, TPB, 0, stream>>>(pts, partKey, masks, out, bar);
    } else {
        fps_pass<1><<<FGRID, TPB, 0, stream>>>(pts, partKey);
        fps_pass<2><<<FGRID, TPB, 0, stream>>>(pts, partKey);
        fps_pass<3><<<FGRID, TPB, 0, stream>>>(pts, partKey);
        fps_final<<<FGRID, TPB, 0, stream>>>(pts, partKey, masks);
        gather_kernel<<<GGRID, TPB, 0, stream>>>(pts, masks, out);
    }
}